// Round 1
// baseline (1317.021 us; speedup 1.0000x reference)
//
#include <hip/hip_runtime.h>
#include <math.h>

#define T_N 2048
#define H_N 2048
#define E_N 32
#define I_N 512
#define NA_MOE (T_N*4)        // 8192 routed assignments
#define NA_ALL (NA_MOE + T_N) // + shared-expert rows = 10240

typedef short s16x8 __attribute__((ext_vector_type(8)));
typedef float f32x4 __attribute__((ext_vector_type(4)));

__device__ inline short f2bf(float f){
    unsigned int u = __float_as_uint(f);
    u = (u + 0x7fffu + ((u >> 16) & 1u)) >> 16;
    return (short)u;
}

// ---------------- cast x (fp32 -> bf16) ----------------
__global__ __launch_bounds__(256) void cast_x_kernel(const float* __restrict__ x,
                                                     short* __restrict__ xbf){
    size_t i = (size_t)(blockIdx.x * 256 + threadIdx.x) * 8;
    float4 a = *(const float4*)(x + i);
    float4 b = *(const float4*)(x + i + 4);
    s16x8 v;
    v[0]=f2bf(a.x); v[1]=f2bf(a.y); v[2]=f2bf(a.z); v[3]=f2bf(a.w);
    v[4]=f2bf(b.x); v[5]=f2bf(b.y); v[6]=f2bf(b.z); v[7]=f2bf(b.w);
    *(s16x8*)(xbf + i) = v;
}

// ---------------- router: logits (fp64 acc), softmax, top4, shared gate ----------------
__global__ __launch_bounds__(64) void router_kernel(
    const float* __restrict__ x, const float* __restrict__ Wr,
    const float* __restrict__ Wsgate,
    float* __restrict__ logits_out, int* __restrict__ tidx, float* __restrict__ tw,
    int* __restrict__ perm, float* __restrict__ wgt, int* __restrict__ counts)
{
    const int t = blockIdx.x, lane = threadIdx.x;
    const float* xr = x + (size_t)t * H_N;
    float xv[32];
    #pragma unroll
    for (int i = 0; i < 32; i++) xv[i] = xr[i*64 + lane];
    __shared__ float lg[34];
    for (int e = 0; e < 33; e++){
        const float* wr = (e < 32) ? (Wr + (size_t)e * H_N) : Wsgate;
        double s = 0.0;
        #pragma unroll
        for (int i = 0; i < 32; i++) s += (double)xv[i] * (double)wr[i*64 + lane];
        #pragma unroll
        for (int o = 32; o > 0; o >>= 1) s += __shfl_down(s, o);
        if (lane == 0) lg[e] = (float)s;
    }
    __syncthreads();
    if (lane < 32) logits_out[(size_t)t*32 + lane] = lg[lane];
    if (lane == 0){
        float m = lg[0];
        for (int e = 1; e < 32; e++) m = fmaxf(m, lg[e]);
        unsigned mask = 0; int sel[4]; float sv[4]; float s4 = 0.f;
        for (int k = 0; k < 4; k++){
            int best = -1; float bv = -1e30f;
            for (int e = 0; e < 32; e++)
                if (!((mask >> e) & 1u) && lg[e] > bv){ bv = lg[e]; best = e; }
            mask |= 1u << best; sel[k] = best;
            float p = expf(lg[best] - m); sv[k] = p; s4 += p;
        }
        for (int k = 0; k < 4; k++){
            tidx[t*4 + k] = sel[k];
            tw[t*4 + k]   = sv[k] / s4;
            atomicAdd(&counts[sel[k]], 1);
        }
        perm[NA_MOE + t] = t;                       // shared expert row
        wgt[NA_MOE + t]  = 1.f / (1.f + expf(-lg[32]));
    }
}

// ---------------- scan: offsets from counts ----------------
__global__ void scan_kernel(int* ctrl){
    if (threadIdx.x == 0){
        int* counts = ctrl; int* eoff = ctrl + 128; int* ecnt = ctrl + 192;
        int acc = 0;
        for (int e = 0; e < 32; e++){ eoff[e] = acc; ecnt[e] = counts[e]; acc += counts[e]; }
        eoff[32] = NA_MOE; ecnt[32] = T_N;
    }
    if (threadIdx.x < 64) ctrl[64 + threadIdx.x] = 0;  // cursors
}

// ---------------- scatter tokens into per-expert lists ----------------
__global__ __launch_bounds__(256) void scatter_kernel(
    const int* __restrict__ tidx, const float* __restrict__ tw,
    int* __restrict__ perm, float* __restrict__ wgt, int* ctrl)
{
    int t = blockIdx.x * 256 + threadIdx.x;
    if (t >= T_N) return;
    const int* eoff = ctrl + 128; int* cursor = ctrl + 64;
    for (int k = 0; k < 4; k++){
        int e = tidx[t*4 + k];
        int pos = eoff[e] + atomicAdd(&cursor[e], 1);
        perm[pos] = t; wgt[pos] = tw[t*4 + k];
    }
}

// ---------------- GEMM1: hact = silu(Xg @ Wg^T) * (Xg @ Wu^T), bf16 out ----------------
__global__ __launch_bounds__(256) void gemm1_kernel(
    const short* __restrict__ xbf,
    const float* __restrict__ Wg, const float* __restrict__ Wu,
    const float* __restrict__ Wsg, const float* __restrict__ Wsu,
    const int* __restrict__ perm, const int* __restrict__ ctrl,
    short* __restrict__ hact)
{
    const int e   = blockIdx.y;
    const int cnt = ctrl[192 + e];
    const int rt  = blockIdx.x;
    if (rt * 64 >= cnt) return;
    const int off = ctrl[128 + e];
    const int n0  = blockIdx.z * 64;

    __shared__ s16x8 lsA[256];
    __shared__ s16x8 lsBg[256];
    __shared__ s16x8 lsBu[256];

    const int tid = threadIdx.x;
    const int tm = tid >> 2, tg = tid & 3;
    const int arow = rt * 64 + tm;
    const short* aptr = (arow < cnt) ? (xbf + (size_t)perm[off + arow] * H_N) : nullptr;
    const float *bgrow, *burow;
    if (e < 32){
        bgrow = Wg + ((size_t)e * I_N + (n0 + tm)) * H_N;
        burow = Wu + ((size_t)e * I_N + (n0 + tm)) * H_N;
    } else {
        bgrow = Wsg + (size_t)(n0 + tm) * H_N;
        burow = Wsu + (size_t)(n0 + tm) * H_N;
    }
    const int wid = tid >> 6, lane = tid & 63;
    const int wm = wid >> 1, wn = wid & 1;
    const int kg = lane >> 4, l15 = lane & 15;

    f32x4 accg[2][2], accu[2][2];
    #pragma unroll
    for (int a = 0; a < 2; a++)
        #pragma unroll
        for (int b = 0; b < 2; b++)
            #pragma unroll
            for (int j = 0; j < 4; j++){ accg[a][b][j] = 0.f; accu[a][b][j] = 0.f; }

    for (int k0 = 0; k0 < H_N; k0 += 32){
        s16x8 av;
        #pragma unroll
        for (int j = 0; j < 8; j++) av[j] = 0;
        if (aptr) av = *(const s16x8*)(aptr + k0 + tg*8);
        lsA[(tg << 6) + tm] = av;
        {
            const float* p = bgrow + k0 + tg*8;
            float4 f0 = *(const float4*)p, f1 = *(const float4*)(p + 4);
            s16x8 v;
            v[0]=f2bf(f0.x); v[1]=f2bf(f0.y); v[2]=f2bf(f0.z); v[3]=f2bf(f0.w);
            v[4]=f2bf(f1.x); v[5]=f2bf(f1.y); v[6]=f2bf(f1.z); v[7]=f2bf(f1.w);
            lsBg[(tg << 6) + tm] = v;
        }
        {
            const float* p = burow + k0 + tg*8;
            float4 f0 = *(const float4*)p, f1 = *(const float4*)(p + 4);
            s16x8 v;
            v[0]=f2bf(f0.x); v[1]=f2bf(f0.y); v[2]=f2bf(f0.z); v[3]=f2bf(f0.w);
            v[4]=f2bf(f1.x); v[5]=f2bf(f1.y); v[6]=f2bf(f1.z); v[7]=f2bf(f1.w);
            lsBu[(tg << 6) + tm] = v;
        }
        __syncthreads();
        #pragma unroll
        for (int mf = 0; mf < 2; mf++){
            s16x8 a = lsA[(kg << 6) + wm*32 + mf*16 + l15];
            #pragma unroll
            for (int nf = 0; nf < 2; nf++){
                s16x8 bg = lsBg[(kg << 6) + wn*32 + nf*16 + l15];
                s16x8 bu = lsBu[(kg << 6) + wn*32 + nf*16 + l15];
                accg[mf][nf] = __builtin_amdgcn_mfma_f32_16x16x32_bf16(a, bg, accg[mf][nf], 0, 0, 0);
                accu[mf][nf] = __builtin_amdgcn_mfma_f32_16x16x32_bf16(a, bu, accu[mf][nf], 0, 0, 0);
            }
        }
        __syncthreads();
    }
    #pragma unroll
    for (int mf = 0; mf < 2; mf++){
        #pragma unroll
        for (int j = 0; j < 4; j++){
            int row = rt*64 + wm*32 + mf*16 + kg*4 + j;
            if (row < cnt){
                #pragma unroll
                for (int nf = 0; nf < 2; nf++){
                    int col = n0 + wn*32 + nf*16 + l15;
                    float g = accg[mf][nf][j], u = accu[mf][nf][j];
                    float h = g / (1.f + expf(-g)) * u;
                    hact[(size_t)(off + row) * I_N + col] = f2bf(h);
                }
            }
        }
    }
}

// ---------------- GEMM2: out[tok] += w * (hact @ Wd^T) ----------------
__global__ __launch_bounds__(256) void gemm2_kernel(
    const short* __restrict__ hact,
    const float* __restrict__ Wd, const float* __restrict__ Wsd,
    const int* __restrict__ perm, const float* __restrict__ wgt,
    const int* __restrict__ ctrl, float* __restrict__ out)
{
    const int e   = blockIdx.y;
    const int cnt = ctrl[192 + e];
    const int rt  = blockIdx.x;
    if (rt * 64 >= cnt) return;
    const int off = ctrl[128 + e];
    const int n0  = blockIdx.z * 64;

    __shared__ s16x8 lsA[256];
    __shared__ s16x8 lsB[256];

    const int tid = threadIdx.x;
    const int tm = tid >> 2, tg = tid & 3;
    const int arow = rt * 64 + tm;
    const short* aptr = (arow < cnt) ? (hact + (size_t)(off + arow) * I_N) : nullptr;
    const float* brow = (e < 32) ? (Wd + ((size_t)e * H_N + (n0 + tm)) * I_N)
                                 : (Wsd + (size_t)(n0 + tm) * I_N);
    const int wid = tid >> 6, lane = tid & 63;
    const int wm = wid >> 1, wn = wid & 1;
    const int kg = lane >> 4, l15 = lane & 15;

    f32x4 acc[2][2];
    #pragma unroll
    for (int a = 0; a < 2; a++)
        #pragma unroll
        for (int b = 0; b < 2; b++)
            #pragma unroll
            for (int j = 0; j < 4; j++) acc[a][b][j] = 0.f;

    for (int k0 = 0; k0 < I_N; k0 += 32){
        s16x8 av;
        #pragma unroll
        for (int j = 0; j < 8; j++) av[j] = 0;
        if (aptr) av = *(const s16x8*)(aptr + k0 + tg*8);
        lsA[(tg << 6) + tm] = av;
        {
            const float* p = brow + k0 + tg*8;
            float4 f0 = *(const float4*)p, f1 = *(const float4*)(p + 4);
            s16x8 v;
            v[0]=f2bf(f0.x); v[1]=f2bf(f0.y); v[2]=f2bf(f0.z); v[3]=f2bf(f0.w);
            v[4]=f2bf(f1.x); v[5]=f2bf(f1.y); v[6]=f2bf(f1.z); v[7]=f2bf(f1.w);
            lsB[(tg << 6) + tm] = v;
        }
        __syncthreads();
        #pragma unroll
        for (int mf = 0; mf < 2; mf++){
            s16x8 a = lsA[(kg << 6) + wm*32 + mf*16 + l15];
            #pragma unroll
            for (int nf = 0; nf < 2; nf++){
                s16x8 b = lsB[(kg << 6) + wn*32 + nf*16 + l15];
                acc[mf][nf] = __builtin_amdgcn_mfma_f32_16x16x32_bf16(a, b, acc[mf][nf], 0, 0, 0);
            }
        }
        __syncthreads();
    }
    #pragma unroll
    for (int mf = 0; mf < 2; mf++){
        #pragma unroll
        for (int j = 0; j < 4; j++){
            int row = rt*64 + wm*32 + mf*16 + kg*4 + j;
            if (row < cnt){
                int aidx = off + row;
                int tok  = perm[aidx];
                float w  = wgt[aidx];
                #pragma unroll
                for (int nf = 0; nf < 2; nf++){
                    int col = n0 + wn*32 + nf*16 + l15;
                    atomicAdd(&out[(size_t)tok * H_N + col], w * acc[mf][nf][j]);
                }
            }
        }
    }
}

extern "C" void kernel_launch(void* const* d_in, const int* in_sizes, int n_in,
                              void* d_out, int out_size, void* d_ws, size_t ws_size,
                              hipStream_t stream)
{
    const float* x      = (const float*)d_in[0];
    const float* Wr     = (const float*)d_in[1];
    const float* Wg     = (const float*)d_in[2];
    const float* Wu     = (const float*)d_in[3];
    const float* Wd     = (const float*)d_in[4];
    const float* Wsg    = (const float*)d_in[5];
    const float* Wsu    = (const float*)d_in[6];
    const float* Wsd    = (const float*)d_in[7];
    const float* Wsgate = (const float*)d_in[8];

    float* out    = (float*)d_out;
    float* logits = out + (size_t)T_N * H_N;

    char* ws = (char*)d_ws;
    short* xbf  = (short*)ws;                    // 8,388,608 B
    short* hact = (short*)(ws + 8388608);        // 10,485,760 B
    int*   perm = (int*)(ws + 18874368);         // 40,960 B
    float* wgt  = (float*)(ws + 18915328);       // 40,960 B
    int*   tidx = (int*)(ws + 18956288);         // 32,768 B
    float* tw   = (float*)(ws + 18989056);       // 32,768 B
    int*   ctrl = (int*)(ws + 19021824);         // 1,024 B: counts[64]|cursor[64]|eoff[64]|ecnt[64]

    hipMemsetAsync(d_out, 0, (size_t)T_N * H_N * sizeof(float), stream);
    hipMemsetAsync(ctrl, 0, 256 * sizeof(int), stream);

    cast_x_kernel<<<2048, 256, 0, stream>>>(x, xbf);
    router_kernel<<<T_N, 64, 0, stream>>>(x, Wr, Wsgate, logits, tidx, tw, perm, wgt, ctrl);
    scan_kernel<<<1, 64, 0, stream>>>(ctrl);
    scatter_kernel<<<T_N/256, 256, 0, stream>>>(tidx, tw, perm, wgt, ctrl);
    gemm1_kernel<<<dim3(32, 33, 8),  256, 0, stream>>>(xbf, Wg, Wu, Wsg, Wsu, perm, ctrl, hact);
    gemm2_kernel<<<dim3(32, 33, 32), 256, 0, stream>>>(hact, Wd, Wsd, perm, wgt, ctrl, out);
}